// Round 3
// baseline (21596.770 us; speedup 1.0000x reference)
//
#include <hip/hip_runtime.h>
#include <math.h>

typedef _Float16 half_t;
typedef _Float16 half8 __attribute__((ext_vector_type(8)));
typedef float f32x4 __attribute__((ext_vector_type(4)));

#define B_ 128
#define T_ 256
#define I_ 512
#define H_ 1024

// ---------------------------------------------------------------------------
// sync helpers (agent scope per guide G16)
__device__ __forceinline__ void wait_ge(int* p, int v) {
    while (__hip_atomic_load(p, __ATOMIC_ACQUIRE, __HIP_MEMORY_SCOPE_AGENT) < v)
        __builtin_amdgcn_s_sleep(2);
}
__device__ __forceinline__ void publish(int* p) {
    __hip_atomic_fetch_add(p, 1, __ATOMIC_RELEASE, __HIP_MEMORY_SCOPE_AGENT);
}

// ---------------------------------------------------------------------------
// prep: x fp32 -> fp16
__global__ void k_convert_x(const float* __restrict__ x, half_t* __restrict__ x16, int n8) {
    int i = blockIdx.x * blockDim.x + threadIdx.x;
    if (i >= n8) return;
    const float4* xv = (const float4*)x;
    float4 a = xv[2 * i], b = xv[2 * i + 1];
    half8 o;
    o[0] = (half_t)a.x; o[1] = (half_t)a.y; o[2] = (half_t)a.z; o[3] = (half_t)a.w;
    o[4] = (half_t)b.x; o[5] = (half_t)b.y; o[6] = (half_t)b.z; o[7] = (half_t)b.w;
    ((half8*)x16)[i] = o;
}

// prep: pack W_ih|W_hh into MFMA B-fragment order (round-1 verified layout):
// [hg(128)][kb(Ktot/32)][nt(2)][lane(64)][j(8)]
// B-frag (16x16x32): lane l holds B[k=(l>>4)*8+j][n=l&15]; col c = nt*16+(l&15);
// gate = c>>3, hoff = c&7; W row = gate*1024 + hg*8 + hoff.
__global__ void k_pack_w(const float* __restrict__ Wih, const float* __restrict__ Whh,
                         half_t* __restrict__ out, int Kx, int Ktot) {
    int idx = blockIdx.x * blockDim.x + threadIdx.x;
    int total = 4096 * Ktot;
    if (idx >= total) return;
    int j = idx & 7;
    int lane = (idx >> 3) & 63;
    int nt = (idx >> 9) & 1;
    int rest = idx >> 10;
    int nkb = Ktot >> 5;
    int kb = rest % nkb;
    int hg = rest / nkb;
    int nl = nt * 16 + (lane & 15);
    int gate = nl >> 3, hoff = nl & 7;
    int row = gate * 1024 + hg * 8 + hoff;
    int k = kb * 32 + (lane >> 4) * 8 + j;
    float v = (k < Kx) ? Wih[(size_t)row * Kx + k] : Whh[(size_t)row * 1024 + (k - Kx)];
    out[idx] = (half_t)v;
}

// bias packed [hg*32 + gate*8 + hoff], b_ih + b_hh summed (round-1 verified)
__global__ void k_pack_bias(const float* __restrict__ bih, const float* __restrict__ bhh,
                            float* __restrict__ out) {
    int idx = blockIdx.x * blockDim.x + threadIdx.x;
    if (idx >= 4096) return;
    int hg = idx >> 5, c = idx & 31;
    int gate = c >> 3, hoff = c & 7;
    int row = gate * 1024 + hg * 8 + hoff;
    out[idx] = bih[row] + bhh[row];
}

__global__ void k_zero(unsigned int* __restrict__ p, int n) {
    int i = blockIdx.x * blockDim.x + threadIdx.x;
    if (i < n) p[i] = 0u;
}

__global__ void k_seed(int* cnt0, int* cnt1) {
    cnt0[0] = 128;
    cnt1[0] = 128;
}

// ---------------------------------------------------------------------------
// One WG owns one (layer, slice): slice = 8 hidx x 4 gates = 32 cols, all 128
// rows, full K. 16 waves = 8 kh (K-split) x 2 mh (rows 0-63 / 64-127); each
// wave does 4 row-tiles of 16. B fragments persist in registers (NKB8*2*4
// VGPRs/lane). K-partials reduced with LDS atomicAdd into pbuf[128][33].
template <int LAYER, int NKB8>
__device__ __forceinline__ void load_b(int slice, const half_t* __restrict__ wp,
                                       half8 (&Breg)[NKB8][2]) {
    constexpr int NKB = NKB8 * 8;
    const half8* w8 = (const half8*)wp;
    int wave = threadIdx.x >> 6, lane = threadIdx.x & 63;
    int kh = wave >> 1;
    size_t base = (size_t)slice * (NKB * 128) + (size_t)kh * (NKB8 * 128);
#pragma unroll
    for (int i = 0; i < NKB8; ++i)
#pragma unroll
        for (int nt = 0; nt < 2; ++nt)
            Breg[i][nt] = w8[base + i * 128 + nt * 64 + lane];
}

template <int LAYER, int NKB8>
__device__ __forceinline__ void step_body(int slice, int t, const half_t* __restrict__ x16,
                                          half_t* __restrict__ h0seq, half_t* __restrict__ h1seq,
                                          const float* __restrict__ biasp,
                                          float* __restrict__ cbuf, float* pbuf,
                                          const half8 (&Breg)[NKB8][2]) {
    int tid = threadIdx.x;
    int wave = tid >> 6, lane = tid & 63;
    int mh = wave & 1, kh = wave >> 1;
    int q = lane >> 4, ml = lane & 15;

    for (int i = tid; i < 128 * 33; i += 1024) pbuf[i] = 0.f;
    __syncthreads();

    f32x4 acc[4][2];
#pragma unroll
    for (int mt = 0; mt < 4; ++mt) { acc[mt][0] = (f32x4)0.f; acc[mt][1] = (f32x4)0.f; }

#pragma unroll
    for (int i = 0; i < NKB8; ++i) {
        int kg = (kh * NKB8 + i) * 32 + q * 8;
#pragma unroll
        for (int mt = 0; mt < 4; ++mt) {
            int row = mh * 64 + mt * 16 + ml;
            const half_t* ap;
            if (LAYER == 0)
                ap = (kg < I_) ? x16 + ((size_t)row * T_ + t) * I_ + kg
                               : h0seq + ((size_t)t * B_ + row) * H_ + (kg - I_);
            else
                ap = (kg < H_) ? h0seq + ((size_t)(t + 1) * B_ + row) * H_ + kg
                               : h1seq + ((size_t)t * B_ + row) * H_ + (kg - H_);
            half8 a = *(const half8*)ap;
            acc[mt][0] = __builtin_amdgcn_mfma_f32_16x16x32_f16(a, Breg[i][0], acc[mt][0], 0, 0, 0);
            acc[mt][1] = __builtin_amdgcn_mfma_f32_16x16x32_f16(a, Breg[i][1], acc[mt][1], 0, 0, 0);
        }
    }

    // C/D layout: col = lane&15, row = (lane>>4)*4 + r (m89-verified)
#pragma unroll
    for (int mt = 0; mt < 4; ++mt)
#pragma unroll
        for (int nt = 0; nt < 2; ++nt)
#pragma unroll
            for (int r = 0; r < 4; ++r) {
                int rr = mh * 64 + mt * 16 + q * 4 + r;
                atomicAdd(&pbuf[rr * 33 + nt * 16 + ml], acc[mt][nt][r]);
            }
    __syncthreads();

    // epilogue: 1024 threads, one (row, hoff) cell each
    {
        int r = tid >> 3, hoff = tid & 7;
        const float* bb = biasp + slice * 32;
        float gi = pbuf[r * 33 + hoff] + bb[hoff];
        float gf = pbuf[r * 33 + 8 + hoff] + bb[8 + hoff];
        float gg = pbuf[r * 33 + 16 + hoff] + bb[16 + hoff];
        float go = pbuf[r * 33 + 24 + hoff] + bb[24 + hoff];
        int hidx = slice * 8 + hoff;
        float* cst = cbuf + LAYER * (B_ * H_);
        float cold = cst[r * H_ + hidx];
        float si = 1.f / (1.f + __expf(-gi));
        float sf = 1.f / (1.f + __expf(-gf));
        float so = 1.f / (1.f + __expf(-go));
        float tg = 1.f - 2.f / (__expf(2.f * gg) + 1.f);
        float cn = sf * cold + si * tg;
        float th = 1.f - 2.f / (__expf(2.f * cn) + 1.f);
        cst[r * H_ + hidx] = cn;
        half_t* outp = (LAYER == 0) ? h0seq : h1seq;
        outp[((size_t)(t + 1) * B_ + r) * H_ + hidx] = (half_t)(so * th);
    }
}

// persistent cooperative kernel: 256 WGs (128 L0-slices + 128 L1-slices)
__global__ __launch_bounds__(1024) void lstm_persist(
    const half_t* __restrict__ x16, half_t* __restrict__ h0seq, half_t* __restrict__ h1seq,
    const half_t* __restrict__ wp0, const half_t* __restrict__ wp1,
    const float* __restrict__ b0p, const float* __restrict__ b1p,
    float* __restrict__ cbuf, int* cnt0, int* cnt1) {
    __shared__ float pbuf[128 * 33];
    int bid = blockIdx.x;
    int slice = bid & 127;
    if (bid < 128) {
        half8 Breg[6][2];
        load_b<0, 6>(slice, wp0, Breg);
        for (int t = 0; t < T_; ++t) {
            if (threadIdx.x == 0) { wait_ge(cnt0 + t, 128); __threadfence(); }
            __syncthreads();
            step_body<0, 6>(slice, t, x16, h0seq, h1seq, b0p, cbuf, pbuf, Breg);
            __syncthreads();  // drain epilogue stores before release
            if (threadIdx.x == 0) publish(cnt0 + t + 1);
        }
    } else {
        half8 Breg[8][2];
        load_b<1, 8>(slice, wp1, Breg);
        for (int t = 0; t < T_; ++t) {
            if (threadIdx.x == 0) {
                wait_ge(cnt0 + t + 1, 128);
                wait_ge(cnt1 + t, 128);
                __threadfence();
            }
            __syncthreads();
            step_body<1, 8>(slice, t, x16, h0seq, h1seq, b1p, cbuf, pbuf, Breg);
            __syncthreads();
            if (threadIdx.x == 0) publish(cnt1 + t + 1);
        }
    }
}

// fallback: pipelined per-step launches; launch k does L0 step k and L1 step
// k-1 — each launch depends only on the previous launch (stream-ordered).
__global__ __launch_bounds__(1024) void lstm_step_fb(
    int k, const half_t* __restrict__ x16, half_t* __restrict__ h0seq,
    half_t* __restrict__ h1seq, const half_t* __restrict__ wp0,
    const half_t* __restrict__ wp1, const float* __restrict__ b0p,
    const float* __restrict__ b1p, float* __restrict__ cbuf) {
    __shared__ float pbuf[128 * 33];
    int bid = blockIdx.x;
    int slice = bid & 127;
    if (bid < 128) {
        if (k >= T_) return;
        half8 Breg[6][2];
        load_b<0, 6>(slice, wp0, Breg);
        step_body<0, 6>(slice, k, x16, h0seq, h1seq, b0p, cbuf, pbuf, Breg);
    } else {
        if (k < 1) return;
        half8 Breg[8][2];
        load_b<1, 8>(slice, wp1, Breg);
        step_body<1, 8>(slice, k - 1, x16, h0seq, h1seq, b1p, cbuf, pbuf, Breg);
    }
}

// final FC
__global__ void k_fc(const half_t* __restrict__ h, const float* __restrict__ Wfc,
                     const float* __restrict__ bfc, float* __restrict__ out) {
    int m = blockIdx.x, lane = threadIdx.x;
    float s = 0.f;
    for (int k = lane; k < H_; k += 64) s += (float)h[m * H_ + k] * Wfc[k];
#pragma unroll
    for (int o = 32; o; o >>= 1) s += __shfl_down(s, o, 64);
    if (lane == 0) out[m] = s + bfc[0];
}

// ---------------------------------------------------------------------------
extern "C" void kernel_launch(void* const* d_in, const int* in_sizes, int n_in,
                              void* d_out, int out_size, void* d_ws, size_t ws_size,
                              hipStream_t stream) {
    const float* x    = (const float*)d_in[0];
    const float* Wih0 = (const float*)d_in[1];
    const float* Whh0 = (const float*)d_in[2];
    const float* bih0 = (const float*)d_in[3];
    const float* bhh0 = (const float*)d_in[4];
    const float* Wih1 = (const float*)d_in[5];
    const float* Whh1 = (const float*)d_in[6];
    const float* bih1 = (const float*)d_in[7];
    const float* bhh1 = (const float*)d_in[8];
    const float* Wfc  = (const float*)d_in[9];
    const float* bfc  = (const float*)d_in[10];
    float* out = (float*)d_out;

    char* ws = (char*)d_ws;
    size_t off = 0;
    auto carve = [&](size_t bytes) { void* p = ws + off; off += (bytes + 255) & ~(size_t)255; return p; };
    half_t* x16   = (half_t*)carve((size_t)B_ * T_ * I_ * 2);        // 33.6 MB
    half_t* h0seq = (half_t*)carve((size_t)(T_ + 1) * B_ * H_ * 2);  // 67.4 MB
    half_t* h1seq = (half_t*)carve((size_t)(T_ + 1) * B_ * H_ * 2);  // 67.4 MB
    half_t* wp0   = (half_t*)carve((size_t)4096 * 1536 * 2);         // 12.6 MB
    half_t* wp1   = (half_t*)carve((size_t)4096 * 2048 * 2);         // 16.8 MB
    float*  b0p   = (float*)carve(4096 * 4);
    float*  b1p   = (float*)carve(4096 * 4);
    float*  cbuf  = (float*)carve((size_t)2 * B_ * H_ * 4);          // 1 MB
    int*    flags = (int*)carve(1024 * 4);
    if (off > ws_size) return;  // total ~198.8 MB; round-2 proved ws >= 215 MB

    int* cnt0 = flags;        // [257]
    int* cnt1 = flags + 512;  // [257]

    // prep
    k_convert_x<<<(B_ * T_ * I_ / 8 + 255) / 256, 256, 0, stream>>>(x, x16, B_ * T_ * I_ / 8);
    k_pack_w<<<(4096 * 1536 + 255) / 256, 256, 0, stream>>>(Wih0, Whh0, wp0, 512, 1536);
    k_pack_w<<<(4096 * 2048 + 255) / 256, 256, 0, stream>>>(Wih1, Whh1, wp1, 1024, 2048);
    k_pack_bias<<<16, 256, 0, stream>>>(bih0, bhh0, b0p);
    k_pack_bias<<<16, 256, 0, stream>>>(bih1, bhh1, b1p);
    k_zero<<<256, 256, 0, stream>>>((unsigned int*)h0seq, 65536);           // slot 0
    k_zero<<<256, 256, 0, stream>>>((unsigned int*)h1seq, 65536);           // slot 0
    k_zero<<<1024, 256, 0, stream>>>((unsigned int*)cbuf, 262144);
    k_zero<<<4, 256, 0, stream>>>((unsigned int*)flags, 1024);
    k_seed<<<1, 1, 0, stream>>>(cnt0, cnt1);

    // try persistent cooperative path; fall back to pipelined per-step launches
    void* args[] = {(void*)&x16, (void*)&h0seq, (void*)&h1seq, (void*)&wp0, (void*)&wp1,
                    (void*)&b0p, (void*)&b1p, (void*)&cbuf, (void*)&cnt0, (void*)&cnt1};
    hipError_t err = hipLaunchCooperativeKernel((void*)lstm_persist, dim3(256), dim3(1024),
                                                args, 0, stream);
    if (err != hipSuccess) {
        (void)hipGetLastError();  // clear sticky error
        for (int k = 0; k < T_ + 1; ++k)
            lstm_step_fb<<<256, 1024, 0, stream>>>(k, x16, h0seq, h1seq, wp0, wp1,
                                                   b0p, b1p, cbuf);
    }

    k_fc<<<128, 64, 0, stream>>>(h1seq + (size_t)T_ * B_ * H_, Wfc, bfc, out);
}

// Round 4
// 12727.374 us; speedup vs baseline: 1.6969x; 1.6969x over previous
//
#include <hip/hip_runtime.h>
#include <math.h>

typedef _Float16 half_t;
typedef _Float16 half8 __attribute__((ext_vector_type(8)));
typedef float f32x4 __attribute__((ext_vector_type(4)));

#define B_ 128
#define T_ 256
#define I_ 512
#define H_ 1024

// ---------------------------------------------------------------------------
// sync helpers (agent scope; protocol validated in round 3)
__device__ __forceinline__ void wait_ge(int* p, int v) {
    while (__hip_atomic_load(p, __ATOMIC_ACQUIRE, __HIP_MEMORY_SCOPE_AGENT) < v)
        __builtin_amdgcn_s_sleep(2);
}
__device__ __forceinline__ void publish(int* p) {
    __hip_atomic_fetch_add(p, 1, __ATOMIC_RELEASE, __HIP_MEMORY_SCOPE_AGENT);
}

// ---------------------------------------------------------------------------
__global__ void k_convert_x(const float* __restrict__ x, half_t* __restrict__ x16, int n8) {
    int i = blockIdx.x * blockDim.x + threadIdx.x;
    if (i >= n8) return;
    const float4* xv = (const float4*)x;
    float4 a = xv[2 * i], b = xv[2 * i + 1];
    half8 o;
    o[0] = (half_t)a.x; o[1] = (half_t)a.y; o[2] = (half_t)a.z; o[3] = (half_t)a.w;
    o[4] = (half_t)b.x; o[5] = (half_t)b.y; o[6] = (half_t)b.z; o[7] = (half_t)b.w;
    ((half8*)x16)[i] = o;
}

// Pack W_ih|W_hh into per-(slice,kh) B-fragment slabs:
// layout [s(64)][kh(2)][kb(NKB2)][nt(4)][lane(64)][j(8)], NKB2 = Ktot/64.
// B-frag (16x16x32): lane l holds B[k=(l>>4)*8+j][n=l&15].
// col-in-slice c = nt*16 + (l&15) -> gate = nt, hoff = l&15;
// W row = nt*1024 + s*16 + hoff; k = kh*(Ktot/2) + kb*32 + (l>>4)*8 + j.
__global__ void k_pack_w3(const float* __restrict__ Wih, const float* __restrict__ Whh,
                          half_t* __restrict__ out, int Kx, int Ktot) {
    int idx = blockIdx.x * blockDim.x + threadIdx.x;
    int total = 4096 * Ktot;
    if (idx >= total) return;
    int nkb2 = Ktot >> 6;
    int j = idx & 7;
    int lane = (idx >> 3) & 63;
    int nt = (idx >> 9) & 3;
    int rest = idx >> 11;
    int kb = rest % nkb2;
    int rest2 = rest / nkb2;
    int kh = rest2 & 1;
    int s = rest2 >> 1;
    int row = nt * 1024 + s * 16 + (lane & 15);
    int k = kh * (Ktot >> 1) + kb * 32 + (lane >> 4) * 8 + j;
    float v = (k < Kx) ? Wih[(size_t)row * Kx + k] : Whh[(size_t)row * 1024 + (k - Kx)];
    out[idx] = (half_t)v;
}

// bias packed bp[s*64 + nt*16 + hoff] = b_ih[row] + b_hh[row], row = nt*1024+s*16+hoff
__global__ void k_pack_bias3(const float* __restrict__ bih, const float* __restrict__ bhh,
                             float* __restrict__ out) {
    int idx = blockIdx.x * blockDim.x + threadIdx.x;
    if (idx >= 4096) return;
    int s = idx >> 6, c = idx & 63;
    int nt = c >> 4, hoff = c & 15;
    int row = nt * 1024 + s * 16 + hoff;
    out[idx] = bih[row] + bhh[row];
}

__global__ void k_zero(unsigned int* __restrict__ p, int n) {
    int i = blockIdx.x * blockDim.x + threadIdx.x;
    if (i < n) p[i] = 0u;
}

__global__ void k_seed(int* cnt0, int* cnt1) {
    cnt0[0] = 128;
    cnt1[0] = 128;
}

// ---------------------------------------------------------------------------
// WG = (layer, slice s in [0,64), row-half rh in {0,1}); 512 threads = 8 waves.
// wave = kh*4 + mh: mh picks a 16-row m-tile, kh picks a K-half.
// Wave holds B-frags for 4 gates x 16 hidx over its K-half in VGPRs (<=128),
// acc = 4 frags (16 VGPR). Each A-frag load feeds 4 MFMAs. kh partials merge
// through a 17 KB LDS buffer (2-way bank alias = free). All 4 gates of an
// output cell land in ONE lane -> register epilogue; c-state in registers.
template <int LAYER, int NKB2, bool PERSIST>
__device__ __forceinline__ void layer_run(
    int slice, int rh, const half_t* __restrict__ x16,
    half_t* __restrict__ h0seq, half_t* __restrict__ h1seq,
    const half_t* __restrict__ wp, const float* __restrict__ bp,
    float* __restrict__ cbuf, int* cnt0, int* cnt1, int t0, int t1,
    float (*pk)[16][68]) {
    constexpr int KTOT = NKB2 * 64;
    constexpr int K2 = KTOT / 2;
    constexpr int KX = LAYER ? 1024 : 512;

    int tid = threadIdx.x;
    int wave = tid >> 6, lane = tid & 63;
    int mh = wave & 3, kh = wave >> 2;
    int q = lane >> 4, ml = lane & 15;
    int row = rh * 64 + mh * 16 + ml;      // A-row this lane loads
    int rowc = rh * 64 + mh * 16 + q * 4;  // C-row base this lane owns (+r)

    // B fragments -> VGPRs (once per kernel)
    half8 Breg[NKB2][4];
    {
        const half8* w8 = (const half8*)wp;
        size_t base = (size_t)(slice * 2 + kh) * NKB2 * 256;
#pragma unroll
        for (int kb = 0; kb < NKB2; ++kb)
#pragma unroll
            for (int nt = 0; nt < 4; ++nt)
                Breg[kb][nt] = w8[base + kb * 256 + nt * 64 + lane];
    }

    float bias_r[4] = {0.f, 0.f, 0.f, 0.f};
    float c_r[4] = {0.f, 0.f, 0.f, 0.f};
    if (kh == 0) {
#pragma unroll
        for (int nt = 0; nt < 4; ++nt) bias_r[nt] = bp[slice * 64 + nt * 16 + ml];
        if (!PERSIST)
#pragma unroll
            for (int r = 0; r < 4; ++r)
                c_r[r] = cbuf[LAYER * (B_ * H_) + (rowc + r) * H_ + slice * 16 + ml];
    }

    for (int t = t0; t < t1; ++t) {
        if (PERSIST) {
            if (tid == 0) {
                if (LAYER == 0) {
                    wait_ge(cnt0 + t, 128);
                } else {
                    wait_ge(cnt0 + t + 1, 128);
                    wait_ge(cnt1 + t, 128);
                }
                __threadfence();
            }
            __syncthreads();
        }
        const half_t* pA0;
        const half_t* pA1;
        if (LAYER == 0) {
            pA0 = x16 + ((size_t)row * T_ + t) * I_;
            pA1 = h0seq + ((size_t)t * B_ + row) * H_;
        } else {
            pA0 = h0seq + ((size_t)(t + 1) * B_ + row) * H_;
            pA1 = h1seq + ((size_t)t * B_ + row) * H_;
        }
        int qo = q * 8;

        f32x4 acc[4];
#pragma unroll
        for (int nt = 0; nt < 4; ++nt) acc[nt] = (f32x4)0.f;

#pragma unroll
        for (int kb = 0; kb < NKB2; ++kb) {
            int kg = kh * K2 + kb * 32;  // wave-uniform
            const half_t* ap = (kg < KX) ? pA0 + kg + qo : pA1 + (kg - KX) + qo;
            half8 a = *(const half8*)ap;
#pragma unroll
            for (int nt = 0; nt < 4; ++nt)
                acc[nt] = __builtin_amdgcn_mfma_f32_16x16x32_f16(a, Breg[kb][nt], acc[nt], 0, 0, 0);
        }

        // merge K-halves: kh=1 writes, kh=0 adds (C/D: col=lane&15, row=q*4+r)
        if (kh == 1) {
#pragma unroll
            for (int nt = 0; nt < 4; ++nt)
#pragma unroll
                for (int r = 0; r < 4; ++r)
                    pk[mh][q * 4 + r][nt * 16 + ml] = acc[nt][r];
        }
        __syncthreads();
        if (kh == 0) {
#pragma unroll
            for (int nt = 0; nt < 4; ++nt)
#pragma unroll
                for (int r = 0; r < 4; ++r)
                    acc[nt][r] += pk[mh][q * 4 + r][nt * 16 + ml];
            half_t* hout = LAYER ? h1seq : h0seq;
#pragma unroll
            for (int r = 0; r < 4; ++r) {
                float gi = acc[0][r] + bias_r[0];
                float gf = acc[1][r] + bias_r[1];
                float gg = acc[2][r] + bias_r[2];
                float go = acc[3][r] + bias_r[3];
                float si = 1.f / (1.f + __expf(-gi));
                float sf = 1.f / (1.f + __expf(-gf));
                float so = 1.f / (1.f + __expf(-go));
                float tg = 1.f - 2.f / (__expf(2.f * gg) + 1.f);
                float cn = sf * c_r[r] + si * tg;
                float th = 1.f - 2.f / (__expf(2.f * cn) + 1.f);
                c_r[r] = cn;
                hout[((size_t)(t + 1) * B_ + rowc + r) * H_ + slice * 16 + ml] = (half_t)(so * th);
            }
        }
        if (PERSIST) {
            __syncthreads();  // drain epilogue stores to L2 before release
            if (tid == 0) publish((LAYER ? cnt1 : cnt0) + t + 1);
        }
    }
    if (!PERSIST && kh == 0) {
#pragma unroll
        for (int r = 0; r < 4; ++r)
            cbuf[LAYER * (B_ * H_) + (rowc + r) * H_ + slice * 16 + ml] = c_r[r];
    }
}

__global__ __launch_bounds__(512, 2) void lstm_persist(
    const half_t* __restrict__ x16, half_t* __restrict__ h0seq, half_t* __restrict__ h1seq,
    const half_t* __restrict__ wp0, const half_t* __restrict__ wp1,
    const float* __restrict__ b0p, const float* __restrict__ b1p,
    float* __restrict__ cbuf, int* cnt0, int* cnt1) {
    __shared__ float pk[4][16][68];
    int bid = blockIdx.x;
    int slice = (bid & 127) >> 1, rh = bid & 1;
    if (bid < 128)
        layer_run<0, 24, true>(slice, rh, x16, h0seq, h1seq, wp0, b0p, cbuf, cnt0, cnt1, 0, T_, pk);
    else
        layer_run<1, 32, true>(slice, rh, x16, h0seq, h1seq, wp1, b1p, cbuf, cnt0, cnt1, 0, T_, pk);
}

// fallback: launch k does L0 step k and L1 step k-1 (stream-ordered pipeline)
__global__ __launch_bounds__(512, 2) void lstm_step_fb(
    int k, const half_t* __restrict__ x16, half_t* __restrict__ h0seq,
    half_t* __restrict__ h1seq, const half_t* __restrict__ wp0,
    const half_t* __restrict__ wp1, const float* __restrict__ b0p,
    const float* __restrict__ b1p, float* __restrict__ cbuf) {
    __shared__ float pk[4][16][68];
    int bid = blockIdx.x;
    int slice = (bid & 127) >> 1, rh = bid & 1;
    if (bid < 128) {
        if (k >= T_) return;
        layer_run<0, 24, false>(slice, rh, x16, h0seq, h1seq, wp0, b0p, cbuf, 0, 0, k, k + 1, pk);
    } else {
        if (k < 1) return;
        layer_run<1, 32, false>(slice, rh, x16, h0seq, h1seq, wp1, b1p, cbuf, 0, 0, k - 1, k, pk);
    }
}

// final FC
__global__ void k_fc(const half_t* __restrict__ h, const float* __restrict__ Wfc,
                     const float* __restrict__ bfc, float* __restrict__ out) {
    int m = blockIdx.x, lane = threadIdx.x;
    float s = 0.f;
    for (int k = lane; k < H_; k += 64) s += (float)h[m * H_ + k] * Wfc[k];
#pragma unroll
    for (int o = 32; o; o >>= 1) s += __shfl_down(s, o, 64);
    if (lane == 0) out[m] = s + bfc[0];
}

// ---------------------------------------------------------------------------
extern "C" void kernel_launch(void* const* d_in, const int* in_sizes, int n_in,
                              void* d_out, int out_size, void* d_ws, size_t ws_size,
                              hipStream_t stream) {
    const float* x    = (const float*)d_in[0];
    const float* Wih0 = (const float*)d_in[1];
    const float* Whh0 = (const float*)d_in[2];
    const float* bih0 = (const float*)d_in[3];
    const float* bhh0 = (const float*)d_in[4];
    const float* Wih1 = (const float*)d_in[5];
    const float* Whh1 = (const float*)d_in[6];
    const float* bih1 = (const float*)d_in[7];
    const float* bhh1 = (const float*)d_in[8];
    const float* Wfc  = (const float*)d_in[9];
    const float* bfc  = (const float*)d_in[10];
    float* out = (float*)d_out;

    char* ws = (char*)d_ws;
    size_t off = 0;
    auto carve = [&](size_t bytes) { void* p = ws + off; off += (bytes + 255) & ~(size_t)255; return p; };
    half_t* x16   = (half_t*)carve((size_t)B_ * T_ * I_ * 2);        // 33.6 MB
    half_t* h0seq = (half_t*)carve((size_t)(T_ + 1) * B_ * H_ * 2);  // 67.4 MB
    half_t* h1seq = (half_t*)carve((size_t)(T_ + 1) * B_ * H_ * 2);  // 67.4 MB
    half_t* wp0   = (half_t*)carve((size_t)4096 * 1536 * 2);         // 12.6 MB
    half_t* wp1   = (half_t*)carve((size_t)4096 * 2048 * 2);         // 16.8 MB
    float*  b0p   = (float*)carve(4096 * 4);
    float*  b1p   = (float*)carve(4096 * 4);
    float*  cbuf  = (float*)carve((size_t)2 * B_ * H_ * 4);          // 1 MB
    int*    flags = (int*)carve(1024 * 4);
    if (off > ws_size) return;  // ~199 MB total; round-2 proved ws >= 215 MB

    int* cnt0 = flags;        // [257]
    int* cnt1 = flags + 512;  // [257]

    k_convert_x<<<(B_ * T_ * I_ / 8 + 255) / 256, 256, 0, stream>>>(x, x16, B_ * T_ * I_ / 8);
    k_pack_w3<<<(4096 * 1536 + 255) / 256, 256, 0, stream>>>(Wih0, Whh0, wp0, 512, 1536);
    k_pack_w3<<<(4096 * 2048 + 255) / 256, 256, 0, stream>>>(Wih1, Whh1, wp1, 1024, 2048);
    k_pack_bias3<<<16, 256, 0, stream>>>(bih0, bhh0, b0p);
    k_pack_bias3<<<16, 256, 0, stream>>>(bih1, bhh1, b1p);
    k_zero<<<256, 256, 0, stream>>>((unsigned int*)h0seq, 65536);   // t=0 slot
    k_zero<<<256, 256, 0, stream>>>((unsigned int*)h1seq, 65536);   // t=0 slot
    k_zero<<<1024, 256, 0, stream>>>((unsigned int*)cbuf, 262144);
    k_zero<<<4, 256, 0, stream>>>((unsigned int*)flags, 1024);
    k_seed<<<1, 1, 0, stream>>>(cnt0, cnt1);

    void* args[] = {(void*)&x16, (void*)&h0seq, (void*)&h1seq, (void*)&wp0, (void*)&wp1,
                    (void*)&b0p, (void*)&b1p, (void*)&cbuf, (void*)&cnt0, (void*)&cnt1};
    hipError_t err = hipLaunchCooperativeKernel((void*)lstm_persist, dim3(256), dim3(512),
                                                args, 0, stream);
    if (err != hipSuccess) {
        (void)hipGetLastError();  // clear sticky error; use pipelined fallback
        for (int k = 0; k < T_ + 1; ++k)
            lstm_step_fb<<<256, 512, 0, stream>>>(k, x16, h0seq, h1seq, wp0, wp1,
                                                  b0p, b1p, cbuf);
    }

    k_fc<<<128, 64, 0, stream>>>(h1seq + (size_t)T_ * B_ * H_, Wfc, bfc, out);
}

// Round 5
// 7948.172 us; speedup vs baseline: 2.7172x; 1.6013x over previous
//
#include <hip/hip_runtime.h>
#include <math.h>

typedef _Float16 half_t;
typedef _Float16 half8 __attribute__((ext_vector_type(8)));
typedef float f32x4 __attribute__((ext_vector_type(4)));

#define B_ 128
#define T_ 256
#define I_ 512
#define H_ 1024

// ---------------------------------------------------------------------------
// sync helpers (agent scope; protocol validated rounds 3-4)
__device__ __forceinline__ void wait_ge(int* p, int v) {
    while (__hip_atomic_load(p, __ATOMIC_ACQUIRE, __HIP_MEMORY_SCOPE_AGENT) < v)
        __builtin_amdgcn_s_sleep(2);
}
__device__ __forceinline__ void publish(int* p) {
    __hip_atomic_fetch_add(p, 1, __ATOMIC_RELEASE, __HIP_MEMORY_SCOPE_AGENT);
}

// ---------------------------------------------------------------------------
// prep: x fp32 [b][t][i] -> fp16 transposed [t][b][i] (contiguous L0 A-reads)
__global__ void k_convert_x(const float* __restrict__ x, half_t* __restrict__ x16t, int n8) {
    int i = blockIdx.x * blockDim.x + threadIdx.x;
    if (i >= n8) return;
    int col8 = i & 63;   // I/8 = 64
    int bt = i >> 6;     // b*T + t
    int b = bt >> 8;     // T = 256
    int t = bt & 255;
    const float4* xv = (const float4*)(x + (size_t)bt * I_);
    float4 a = xv[col8 * 2], c = xv[col8 * 2 + 1];
    half8 o;
    o[0] = (half_t)a.x; o[1] = (half_t)a.y; o[2] = (half_t)a.z; o[3] = (half_t)a.w;
    o[4] = (half_t)c.x; o[5] = (half_t)c.y; o[6] = (half_t)c.z; o[7] = (half_t)c.w;
    ((half8*)(x16t + ((size_t)t * B_ + b) * I_))[col8] = o;
}

// Pack W_ih|W_hh into per-(slice s, K-quarter kh, gate-pair gp) B-frag slabs:
// [s(64)][kh(4)][gp(2)][kb(NKBW)][nt(2)][lane(64)][j(8)], NKBW = Ktot/128.
// B-frag (16x16x32): lane l holds B[k=(l>>4)*8+j][n=l&15].
// gate = gp*2+nt; W row = gate*1024 + s*16 + (l&15);
// k = kh*(Ktot/4) + kb*32 + (l>>4)*8 + j.
__global__ void k_pack_w4(const float* __restrict__ Wih, const float* __restrict__ Whh,
                          half_t* __restrict__ out, int Kx, int Ktot) {
    long long idx = blockIdx.x * (long long)blockDim.x + threadIdx.x;
    long long total = 4096LL * Ktot;
    if (idx >= total) return;
    int NKBW = Ktot >> 7;
    int j = idx & 7;
    int lane = (idx >> 3) & 63;
    int nt = (idx >> 9) & 1;
    int kb = (int)((idx >> 10) % NKBW);
    int rest = (int)((idx >> 10) / NKBW);
    int gp = rest & 1, kh = (rest >> 1) & 3, s = rest >> 3;
    int gate = gp * 2 + nt;
    int row = gate * 1024 + s * 16 + (lane & 15);
    int k = kh * (Ktot >> 2) + kb * 32 + ((lane >> 4) << 3) + j;
    float v = (k < Kx) ? Wih[(size_t)row * Kx + k] : Whh[(size_t)row * 1024 + (k - Kx)];
    out[idx] = (half_t)v;
}

// bias packed bp[s*64 + gate*16 + hoff] = b_ih[row]+b_hh[row], row = gate*1024+s*16+hoff
__global__ void k_pack_bias3(const float* __restrict__ bih, const float* __restrict__ bhh,
                             float* __restrict__ out) {
    int idx = blockIdx.x * blockDim.x + threadIdx.x;
    if (idx >= 4096) return;
    int s = idx >> 6, c = idx & 63;
    int nt = c >> 4, hoff = c & 15;
    int row = nt * 1024 + s * 16 + hoff;
    out[idx] = bih[row] + bhh[row];
}

__global__ void k_zero(unsigned int* __restrict__ p, int n) {
    int i = blockIdx.x * blockDim.x + threadIdx.x;
    if (i < n) p[i] = 0u;
}

__global__ void k_seed(int* cnt0, int* cnt1) {
    cnt0[0] = 128;
    cnt1[0] = 128;
}

// ---------------------------------------------------------------------------
// WG = (layer, slice s in [0,64), row-half rh). 512 threads = 8 waves:
// wave = kh*2 + gp. Wave holds DISTINCT B chunk (32 cols x K/4) in VGPRs:
// L1 128 VGPR, L0 96. Each wave MFMAs 4 m-tiles (64 rows) x 2 n-frags.
// K-merge: kh2->R0, kh3->R1 (write); kh0 += R0, kh1 += R1 then write R1;
// kh0 += R1 -> final into pf; epilogue per-cell in registers (c-state regs).
template <int LAYER, int NKBW, bool PERSIST>
__device__ __forceinline__ void layer_run(
    int s, int rh, const half_t* __restrict__ x16t,
    half_t* __restrict__ h0seq, half_t* __restrict__ h1seq,
    const half_t* __restrict__ wp, const float* __restrict__ bp,
    float* __restrict__ cbuf, int* cnt0, int* cnt1, int t0, int t1,
    float (*pbufR)[64][68], float (*pf)[68]) {
    constexpr int KTOT = NKBW * 128;
    constexpr int K4 = KTOT / 4;
    constexpr int KX = LAYER ? 1024 : 512;

    int tid = threadIdx.x;
    int wave = tid >> 6, lane = tid & 63;
    int gp = wave & 1, kh = wave >> 1;
    int q = lane >> 4, ml = lane & 15;

    // distinct B chunk -> VGPRs (once)
    half8 Breg[NKBW][2];
    {
        const half8* w8 = (const half8*)wp;
        size_t base = (size_t)((s * 8 + kh * 2 + gp) * NKBW) * 128;
#pragma unroll
        for (int kb = 0; kb < NKBW; ++kb) {
            Breg[kb][0] = w8[base + kb * 128 + lane];
            Breg[kb][1] = w8[base + kb * 128 + 64 + lane];
        }
    }

    // epilogue-role constants: thread handles cells idx=tid and tid+512;
    // cell: r = idx>>4 (0..63), h = idx&15
    float c_r[2] = {0.f, 0.f};
    float bias_r[2][4];
#pragma unroll
    for (int e = 0; e < 2; ++e) {
        int h = (tid + 512 * e) & 15;
#pragma unroll
        for (int g = 0; g < 4; ++g) bias_r[e][g] = bp[s * 64 + g * 16 + h];
        if (!PERSIST) {
            int r = (tid + 512 * e) >> 4;
            c_r[e] = cbuf[LAYER * (B_ * H_) + (rh * 64 + r) * H_ + s * 16 + h];
        }
    }

    for (int t = t0; t < t1; ++t) {
        if (PERSIST) {
            if (tid == 0) {
                if (LAYER == 0) {
                    wait_ge(cnt0 + t, 128);
                } else {
                    wait_ge(cnt0 + t + 1, 128);
                    wait_ge(cnt1 + t, 128);
                }
                __threadfence();
            }
            __syncthreads();
        }

        const half_t* ax[4];
        const half_t* ah[4];
#pragma unroll
        for (int mt = 0; mt < 4; ++mt) {
            int row = rh * 64 + mt * 16 + ml;
            if (LAYER == 0) {
                ax[mt] = x16t + ((size_t)t * B_ + row) * I_;
                ah[mt] = h0seq + ((size_t)t * B_ + row) * H_;
            } else {
                ax[mt] = h0seq + ((size_t)(t + 1) * B_ + row) * H_;
                ah[mt] = h1seq + ((size_t)t * B_ + row) * H_;
            }
        }

        f32x4 acc[4][2];
#pragma unroll
        for (int mt = 0; mt < 4; ++mt) { acc[mt][0] = (f32x4)0.f; acc[mt][1] = (f32x4)0.f; }

#pragma unroll
        for (int kb = 0; kb < NKBW; ++kb) {
            int kgu = kh * K4 + kb * 32;   // wave-uniform
            int k = kgu + q * 8;
#pragma unroll
            for (int mt = 0; mt < 4; ++mt) {
                const half_t* ap = (kgu < KX) ? ax[mt] + k : ah[mt] + (k - KX);
                half8 a = *(const half8*)ap;
                acc[mt][0] = __builtin_amdgcn_mfma_f32_16x16x32_f16(a, Breg[kb][0], acc[mt][0], 0, 0, 0);
                acc[mt][1] = __builtin_amdgcn_mfma_f32_16x16x32_f16(a, Breg[kb][1], acc[mt][1], 0, 0, 0);
            }
        }

        // K-merge (C/D layout: col=lane&15, row=q*4+r). cc = gate*16 + hoff.
        if (kh >= 2) {
#pragma unroll
            for (int mt = 0; mt < 4; ++mt)
#pragma unroll
                for (int nt = 0; nt < 2; ++nt)
#pragma unroll
                    for (int r = 0; r < 4; ++r)
                        pbufR[kh - 2][mt * 16 + q * 4 + r][gp * 32 + nt * 16 + ml] = acc[mt][nt][r];
        }
        __syncthreads();
        if (kh == 0) {
#pragma unroll
            for (int mt = 0; mt < 4; ++mt)
#pragma unroll
                for (int nt = 0; nt < 2; ++nt)
#pragma unroll
                    for (int r = 0; r < 4; ++r)
                        acc[mt][nt][r] += pbufR[0][mt * 16 + q * 4 + r][gp * 32 + nt * 16 + ml];
        } else if (kh == 1) {
#pragma unroll
            for (int mt = 0; mt < 4; ++mt)
#pragma unroll
                for (int nt = 0; nt < 2; ++nt)
#pragma unroll
                    for (int r = 0; r < 4; ++r) {
                        int rr = mt * 16 + q * 4 + r, cc = gp * 32 + nt * 16 + ml;
                        pbufR[1][rr][cc] += acc[mt][nt][r];
                    }
        }
        __syncthreads();
        if (kh == 0) {
#pragma unroll
            for (int mt = 0; mt < 4; ++mt)
#pragma unroll
                for (int nt = 0; nt < 2; ++nt)
#pragma unroll
                    for (int r = 0; r < 4; ++r) {
                        int rr = mt * 16 + q * 4 + r, cc = gp * 32 + nt * 16 + ml;
                        pf[rr][cc] = acc[mt][nt][r] + pbufR[1][rr][cc];
                    }
        }
        __syncthreads();

        // epilogue: 2 cells per thread, all state in registers
        half_t* hout = LAYER ? h1seq : h0seq;
#pragma unroll
        for (int e = 0; e < 2; ++e) {
            int idx = tid + 512 * e;
            int r = idx >> 4, h = idx & 15;
            float gi = pf[r][h] + bias_r[e][0];
            float gf = pf[r][16 + h] + bias_r[e][1];
            float gg = pf[r][32 + h] + bias_r[e][2];
            float go = pf[r][48 + h] + bias_r[e][3];
            float si = 1.f / (1.f + __expf(-gi));
            float sf = 1.f / (1.f + __expf(-gf));
            float so = 1.f / (1.f + __expf(-go));
            float tg = 1.f - 2.f / (__expf(2.f * gg) + 1.f);
            float cn = sf * c_r[e] + si * tg;
            float th = 1.f - 2.f / (__expf(2.f * cn) + 1.f);
            c_r[e] = cn;
            hout[((size_t)(t + 1) * B_ + rh * 64 + r) * H_ + s * 16 + h] = (half_t)(so * th);
        }

        if (PERSIST) {
            __syncthreads();  // drain epilogue stores before release
            if (tid == 0) publish((LAYER ? cnt1 : cnt0) + t + 1);
        }
    }

    if (!PERSIST) {
#pragma unroll
        for (int e = 0; e < 2; ++e) {
            int idx = tid + 512 * e;
            int r = idx >> 4, h = idx & 15;
            cbuf[LAYER * (B_ * H_) + (rh * 64 + r) * H_ + s * 16 + h] = c_r[e];
        }
    }
}

__global__ __launch_bounds__(512, 2) void lstm_persist(
    const half_t* __restrict__ x16t, half_t* __restrict__ h0seq, half_t* __restrict__ h1seq,
    const half_t* __restrict__ wp0, const half_t* __restrict__ wp1,
    const float* __restrict__ b0p, const float* __restrict__ b1p,
    float* __restrict__ cbuf, int* cnt0, int* cnt1) {
    __shared__ float pbufR[2][64][68];
    __shared__ float pf[64][68];
    int bid = blockIdx.x;
    int s = (bid & 127) >> 1, rh = bid & 1;
    if (bid < 128)
        layer_run<0, 12, true>(s, rh, x16t, h0seq, h1seq, wp0, b0p, cbuf, cnt0, cnt1, 0, T_, pbufR, pf);
    else
        layer_run<1, 16, true>(s, rh, x16t, h0seq, h1seq, wp1, b1p, cbuf, cnt0, cnt1, 0, T_, pbufR, pf);
}

// fallback: launch k does L0 step k and L1 step k-1 (stream-ordered pipeline)
__global__ __launch_bounds__(512, 2) void lstm_step_fb(
    int k, const half_t* __restrict__ x16t, half_t* __restrict__ h0seq,
    half_t* __restrict__ h1seq, const half_t* __restrict__ wp0,
    const half_t* __restrict__ wp1, const float* __restrict__ b0p,
    const float* __restrict__ b1p, float* __restrict__ cbuf) {
    __shared__ float pbufR[2][64][68];
    __shared__ float pf[64][68];
    int bid = blockIdx.x;
    int s = (bid & 127) >> 1, rh = bid & 1;
    if (bid < 128) {
        if (k >= T_) return;
        layer_run<0, 12, false>(s, rh, x16t, h0seq, h1seq, wp0, b0p, cbuf, 0, 0, k, k + 1, pbufR, pf);
    } else {
        if (k < 1) return;
        layer_run<1, 16, false>(s, rh, x16t, h0seq, h1seq, wp1, b1p, cbuf, 0, 0, k - 1, k, pbufR, pf);
    }
}

// final FC
__global__ void k_fc(const half_t* __restrict__ h, const float* __restrict__ Wfc,
                     const float* __restrict__ bfc, float* __restrict__ out) {
    int m = blockIdx.x, lane = threadIdx.x;
    float s = 0.f;
    for (int k = lane; k < H_; k += 64) s += (float)h[m * H_ + k] * Wfc[k];
#pragma unroll
    for (int o = 32; o; o >>= 1) s += __shfl_down(s, o, 64);
    if (lane == 0) out[m] = s + bfc[0];
}

// ---------------------------------------------------------------------------
extern "C" void kernel_launch(void* const* d_in, const int* in_sizes, int n_in,
                              void* d_out, int out_size, void* d_ws, size_t ws_size,
                              hipStream_t stream) {
    const float* x    = (const float*)d_in[0];
    const float* Wih0 = (const float*)d_in[1];
    const float* Whh0 = (const float*)d_in[2];
    const float* bih0 = (const float*)d_in[3];
    const float* bhh0 = (const float*)d_in[4];
    const float* Wih1 = (const float*)d_in[5];
    const float* Whh1 = (const float*)d_in[6];
    const float* bih1 = (const float*)d_in[7];
    const float* bhh1 = (const float*)d_in[8];
    const float* Wfc  = (const float*)d_in[9];
    const float* bfc  = (const float*)d_in[10];
    float* out = (float*)d_out;

    char* ws = (char*)d_ws;
    size_t off = 0;
    auto carve = [&](size_t bytes) { void* p = ws + off; off += (bytes + 255) & ~(size_t)255; return p; };
    half_t* x16t  = (half_t*)carve((size_t)B_ * T_ * I_ * 2);        // 33.6 MB
    half_t* h0seq = (half_t*)carve((size_t)(T_ + 1) * B_ * H_ * 2);  // 67.4 MB
    half_t* h1seq = (half_t*)carve((size_t)(T_ + 1) * B_ * H_ * 2);  // 67.4 MB
    half_t* wp0   = (half_t*)carve((size_t)4096 * 1536 * 2);         // 12.6 MB
    half_t* wp1   = (half_t*)carve((size_t)4096 * 2048 * 2);         // 16.8 MB
    float*  b0p   = (float*)carve(4096 * 4);
    float*  b1p   = (float*)carve(4096 * 4);
    float*  cbuf  = (float*)carve((size_t)2 * B_ * H_ * 4);          // 1 MB
    int*    flags = (int*)carve(1024 * 4);
    if (off > ws_size) return;  // ~199 MB; round-2 proved ws >= 215 MB

    int* cnt0 = flags;        // [257]
    int* cnt1 = flags + 512;  // [257]

    k_convert_x<<<(B_ * T_ * I_ / 8 + 255) / 256, 256, 0, stream>>>(x, x16t, B_ * T_ * I_ / 8);
    k_pack_w4<<<(4096 * 1536 + 255) / 256, 256, 0, stream>>>(Wih0, Whh0, wp0, 512, 1536);
    k_pack_w4<<<(4096 * 2048 + 255) / 256, 256, 0, stream>>>(Wih1, Whh1, wp1, 1024, 2048);
    k_pack_bias3<<<16, 256, 0, stream>>>(bih0, bhh0, b0p);
    k_pack_bias3<<<16, 256, 0, stream>>>(bih1, bhh1, b1p);
    k_zero<<<256, 256, 0, stream>>>((unsigned int*)h0seq, 65536);   // t=0 slot
    k_zero<<<256, 256, 0, stream>>>((unsigned int*)h1seq, 65536);   // t=0 slot
    k_zero<<<1024, 256, 0, stream>>>((unsigned int*)cbuf, 262144);
    k_zero<<<4, 256, 0, stream>>>((unsigned int*)flags, 1024);
    k_seed<<<1, 1, 0, stream>>>(cnt0, cnt1);

    void* args[] = {(void*)&x16t, (void*)&h0seq, (void*)&h1seq, (void*)&wp0, (void*)&wp1,
                    (void*)&b0p, (void*)&b1p, (void*)&cbuf, (void*)&cnt0, (void*)&cnt1};
    hipError_t err = hipLaunchCooperativeKernel((void*)lstm_persist, dim3(256), dim3(512),
                                                args, 0, stream);
    if (err != hipSuccess) {
        (void)hipGetLastError();  // clear sticky error; pipelined fallback
        for (int k = 0; k < T_ + 1; ++k)
            lstm_step_fb<<<256, 512, 0, stream>>>(k, x16t, h0seq, h1seq, wp0, wp1,
                                                  b0p, b1p, cbuf);
    }

    k_fc<<<128, 64, 0, stream>>>(h1seq + (size_t)T_ * B_ * H_, Wfc, bfc, out);
}